// Round 2
// baseline (43.086 us; speedup 1.0000x reference)
//
#include <hip/hip_runtime.h>

typedef __attribute__((ext_vector_type(8))) short short8;
typedef __attribute__((ext_vector_type(16))) float f32x16;
typedef __attribute__((ext_vector_type(2))) float f32x2;
typedef __attribute__((ext_vector_type(4))) float f32x4u __attribute__((aligned(4)));
typedef __attribute__((ext_vector_type(2))) unsigned int uint2v;

#define C_INPUT 16
#define C_OUTPUT 32
#define DIM 1024
#define HW 1026
#define CH_STRIDE (HW * HW)        /* 1052676 */
#define TH 16                      /* output rows per block   */
#define TW 32                      /* output cols per block   */
#define LDS_ROWS 18                /* TH + 2 halo             */
#define LDS_W 34                   /* TW + 2 halo             */
#define ROW_BYTES (LDS_W * 32)     /* 34 px * 16ch * 2B = 1088 */
#define LDS_BYTES (LDS_ROWS * ROW_BYTES) /* 19584 B */
#define NUNITS (4 * LDS_ROWS * 9)  /* 648 units of 4ch x 4px */

__device__ __forceinline__ unsigned short f2bf(float f) {
    // fp32 -> bf16 round-to-nearest-even
    unsigned int u = __builtin_bit_cast(unsigned int, f);
    u += 0x7fffu + ((u >> 16) & 1u);
    return (unsigned short)(u >> 16);
}

__global__ __launch_bounds__(256, 4)
void gck3x3_mfma_kernel(const float* __restrict__ x,
                        const float* __restrict__ kern,
                        float* __restrict__ out) {
    __shared__ __attribute__((aligned(16))) unsigned char s_x[LDS_BYTES];

    const int tid  = threadIdx.x;
    const int lane = tid & 63;
    const int wv   = tid >> 6;      // wave id 0..3
    const int n    = lane & 31;     // N index (pixel) / outch for A-load
    const int hi   = lane >> 5;     // k-group: channels 8*hi .. 8*hi+7

    // XCD-aware bijective swizzle: nwg = 2048 = 8 * 256
    const int bid = blockIdx.x;
    const int swz = (bid & 7) * 256 + (bid >> 3);
    const int bh  = swz >> 5;       // 0..63
    const int bw  = swz & 31;       // 0..31
    const int h0  = bh * TH;
    const int w0  = bw * TW;

    // ---- staging phase 1: issue ALL global loads (4ch x 4px units) ----
    // unit idx -> c4 (channel quad), row, wq (pixel quad)
    f32x4u vals[3][4];
    #pragma unroll
    for (int k = 0; k < 3; ++k) {
        const int idx = tid + k * 256;
        if (idx < NUNITS) {
            const int c4  = idx / (LDS_ROWS * 9);
            const int rem = idx - c4 * (LDS_ROWS * 9);
            const int row = rem / 9;
            const int wq  = rem - row * 9;
            const int w   = wq * 4;
            const float* base = x + (4 * c4) * CH_STRIDE + (h0 + row) * HW + (w0 + w);
            if (wq < 8) {
                #pragma unroll
                for (int j = 0; j < 4; ++j)
                    vals[k][j] = *(const f32x4u*)(base + j * CH_STRIDE);
            } else {
                // tail quad: only 2 px valid (avoid OOB read past row end)
                #pragma unroll
                for (int j = 0; j < 4; ++j) {
                    f32x2 t2 = *(const f32x2*)(base + j * CH_STRIDE);
                    f32x4u v; v[0] = t2[0]; v[1] = t2[1]; v[2] = 0.f; v[3] = 0.f;
                    vals[k][j] = v;
                }
            }
        }
    }

    // ---- staging phase 2: convert + transpose to LDS [row][px][16ch] ----
    #pragma unroll
    for (int k = 0; k < 3; ++k) {
        const int idx = tid + k * 256;
        if (idx < NUNITS) {
            const int c4  = idx / (LDS_ROWS * 9);
            const int rem = idx - c4 * (LDS_ROWS * 9);
            const int row = rem / 9;
            const int wq  = rem - row * 9;
            const int w   = wq * 4;
            const int nv  = (wq < 8) ? 4 : 2;
            #pragma unroll
            for (int p = 0; p < 4; ++p) {
                if (p < nv) {
                    const int pp = w + p;
                    const unsigned int lo  = (unsigned int)f2bf(vals[k][0][p]) |
                                             ((unsigned int)f2bf(vals[k][1][p]) << 16);
                    const unsigned int hi2 = (unsigned int)f2bf(vals[k][2][p]) |
                                             ((unsigned int)f2bf(vals[k][3][p]) << 16);
                    const int s16 = ((c4 >> 1) ^ (pp >> 2) ^ (pp >> 3)) & 1;
                    const int off = row * ROW_BYTES + pp * 32 + s16 * 16 + (c4 & 1) * 8;
                    uint2v t; t.x = lo; t.y = hi2;
                    *(uint2v*)(s_x + off) = t;
                }
            }
        }
    }

    // ---- A fragments: W[o = lane&31][c = 8*hi + j][r][s], fp32 -> bf16 ----
    // (L2-resident 18 KB; loaded while LDS writes / barrier drain)
    short8 af[3][3];
    {
        const int o = n;
        #pragma unroll
        for (int r = 0; r < 3; ++r) {
            #pragma unroll
            for (int s = 0; s < 3; ++s) {
                short8 v;
                #pragma unroll
                for (int j = 0; j < 8; ++j) {
                    const int c = 8 * hi + j;
                    v[j] = (short)f2bf(kern[o * 144 + c * 9 + r * 3 + s]);
                }
                af[r][s] = v;
            }
        }
    }

    __syncthreads();

    // ---- rolling compute+store: one 16-acc tile live at a time ----
    #pragma unroll
    for (int t = 0; t < 4; ++t) {
        const int baserow = wv * 4 + t;              // output row within tile
        f32x16 acc;
        #pragma unroll
        for (int q = 0; q < 16; ++q) acc[q] = 0.0f;

        #pragma unroll
        for (int r = 0; r < 3; ++r) {
            #pragma unroll
            for (int s = 0; s < 3; ++s) {
                const int w   = n + s;
                const int s16 = (hi ^ (w >> 2) ^ (w >> 3)) & 1;
                const int off = (baserow + r) * ROW_BYTES + w * 32 + s16 * 16;
                const short8 bfr = *(const short8*)(s_x + off);   // ds_read_b128
                acc = __builtin_amdgcn_mfma_f32_32x32x16_bf16(af[r][s], bfr, acc, 0, 0, 0);
            }
        }

        // epilogue: C/D layout col = lane&31, row(outch) = (q&3)+8*(q>>2)+4*hi
        const int h = h0 + baserow;
        #pragma unroll
        for (int q = 0; q < 16; ++q) {
            const int o = (q & 3) + 8 * (q >> 2) + 4 * hi;
            __builtin_nontemporal_store(acc[q], out + (o << 20) + (h << 10) + (w0 + n));
        }
    }
}

extern "C" void kernel_launch(void* const* d_in, const int* in_sizes, int n_in,
                              void* d_out, int out_size, void* d_ws, size_t ws_size,
                              hipStream_t stream) {
    (void)in_sizes; (void)n_in; (void)d_ws; (void)ws_size; (void)out_size;
    const float* x    = (const float*)d_in[0];
    const float* kern = (const float*)d_in[1];
    float*       out  = (float*)d_out;
    gck3x3_mfma_kernel<<<2048, 256, 0, stream>>>(x, kern, out);
}